// Round 5
// baseline (75.742 us; speedup 1.0000x reference)
//
#include <hip/hip_runtime.h>

#define DIM 64

// CSR SpMM: out[i,:] = sum_k values[k] * x[indices[k],:]
// One wave handles TWO rows (2w, 2w+1) in lockstep so both rows' dependency
// chains (indices -> gather) are in flight simultaneously: 8 x 1KiB gathers
// outstanding per wave. Wave split into 4 x 16-lane groups; group g owns edges
// k+4g..k+4g+3 of each row (one int4 + one float4 broadcast load per group).
// Lane holds 4 consecutive columns (float4). Row-end: shfl_xor(16,32) butterfly.
__global__ __launch_bounds__(256) void spmm_dualrow_kernel(
    const float* __restrict__ x,
    const int*   __restrict__ indptr,
    const int*   __restrict__ indices,
    const float* __restrict__ values,
    float*       __restrict__ out,
    int n_nodes, int n_edges)
{
    const int wave = (int)((blockIdx.x * blockDim.x + threadIdx.x) >> 6);
    const int lane = (int)(threadIdx.x & 63);
    const int rowA = wave << 1;
    const int rowB = rowA + 1;
    if (rowA >= n_nodes) return;

    const int g = lane >> 4;                          // edge-group 0..3
    const unsigned col4 = (unsigned)(lane & 15) << 2; // this lane's 4 columns

    const int sA = indptr[rowA];
    const int eA = indptr[rowA + 1];
    const int eB = (rowB < n_nodes) ? indptr[rowB + 1] : eA;
    // row B starts where row A ends (CSR)
    int kA = sA, kB = eA;
    const int endA = eA, endB = eB;

    float axA=0.f, ayA=0.f, azA=0.f, awA=0.f;
    float axB=0.f, ayB=0.f, azB=0.f, awB=0.f;

    while (kA < endA || kB < endB) {
        if ((kA + 15 < n_edges) && (kB + 15 < n_edges)) {
            // ---- fast straight-line path: both rows' loads issued together ----
            const int baseA = kA + (g << 2);
            const int baseB = kB + (g << 2);
            const int4   cA = *(const int4*)  (indices + baseA);
            const float4 vA = *(const float4*)(values  + baseA);
            const int4   cB = *(const int4*)  (indices + baseB);
            const float4 vB = *(const float4*)(values  + baseB);

            const float wA0 = (baseA + 0 < endA) ? vA.x : 0.f;
            const float wA1 = (baseA + 1 < endA) ? vA.y : 0.f;
            const float wA2 = (baseA + 2 < endA) ? vA.z : 0.f;
            const float wA3 = (baseA + 3 < endA) ? vA.w : 0.f;
            const float wB0 = (baseB + 0 < endB) ? vB.x : 0.f;
            const float wB1 = (baseB + 1 < endB) ? vB.y : 0.f;
            const float wB2 = (baseB + 2 < endB) ? vB.z : 0.f;
            const float wB3 = (baseB + 3 < endB) ? vB.w : 0.f;

            const float4 aA0 = *(const float4*)(x + (((unsigned)cA.x) << 6) + col4);
            const float4 aA1 = *(const float4*)(x + (((unsigned)cA.y) << 6) + col4);
            const float4 aA2 = *(const float4*)(x + (((unsigned)cA.z) << 6) + col4);
            const float4 aA3 = *(const float4*)(x + (((unsigned)cA.w) << 6) + col4);
            const float4 aB0 = *(const float4*)(x + (((unsigned)cB.x) << 6) + col4);
            const float4 aB1 = *(const float4*)(x + (((unsigned)cB.y) << 6) + col4);
            const float4 aB2 = *(const float4*)(x + (((unsigned)cB.z) << 6) + col4);
            const float4 aB3 = *(const float4*)(x + (((unsigned)cB.w) << 6) + col4);

            axA += wA0*aA0.x; ayA += wA0*aA0.y; azA += wA0*aA0.z; awA += wA0*aA0.w;
            axA += wA1*aA1.x; ayA += wA1*aA1.y; azA += wA1*aA1.z; awA += wA1*aA1.w;
            axA += wA2*aA2.x; ayA += wA2*aA2.y; azA += wA2*aA2.z; awA += wA2*aA2.w;
            axA += wA3*aA3.x; ayA += wA3*aA3.y; azA += wA3*aA3.z; awA += wA3*aA3.w;
            axB += wB0*aB0.x; ayB += wB0*aB0.y; azB += wB0*aB0.z; awB += wB0*aB0.w;
            axB += wB1*aB1.x; ayB += wB1*aB1.y; azB += wB1*aB1.z; awB += wB1*aB1.w;
            axB += wB2*aB2.x; ayB += wB2*aB2.y; azB += wB2*aB2.z; awB += wB2*aB2.w;
            axB += wB3*aB3.x; ayB += wB3*aB3.y; azB += wB3*aB3.z; awB += wB3*aB3.w;

            kA = (kA < endA) ? kA + 16 : kA;
            kB = (kB < endB) ? kB + 16 : kB;
        } else {
            // ---- global edge-array tail (last wave only): exact scalar path ----
            for (; kA < endA; ++kA) {
                const float w = (g == 0) ? values[kA] : 0.f;
                const float4 a = *(const float4*)(x + (((unsigned)indices[kA]) << 6) + col4);
                axA += w*a.x; ayA += w*a.y; azA += w*a.z; awA += w*a.w;
            }
            for (; kB < endB; ++kB) {
                const float w = (g == 0) ? values[kB] : 0.f;
                const float4 a = *(const float4*)(x + (((unsigned)indices[kB]) << 6) + col4);
                axB += w*a.x; ayB += w*a.y; azB += w*a.z; awB += w*a.w;
            }
            break;
        }
    }

    // Sum the 4 groups: lanes {l, l^16, l^32, l^48} hold the same columns.
    axA += __shfl_xor(axA,16); ayA += __shfl_xor(ayA,16);
    azA += __shfl_xor(azA,16); awA += __shfl_xor(awA,16);
    axA += __shfl_xor(axA,32); ayA += __shfl_xor(ayA,32);
    azA += __shfl_xor(azA,32); awA += __shfl_xor(awA,32);
    axB += __shfl_xor(axB,16); ayB += __shfl_xor(ayB,16);
    azB += __shfl_xor(azB,16); awB += __shfl_xor(awB,16);
    axB += __shfl_xor(axB,32); ayB += __shfl_xor(ayB,32);
    azB += __shfl_xor(azB,32); awB += __shfl_xor(awB,32);

    if (lane < 16) {
        float4 r; r.x = axA; r.y = ayA; r.z = azA; r.w = awA;
        *(float4*)(out + ((size_t)rowA << 6) + col4) = r;
    } else if (lane < 32 && rowB < n_nodes) {
        float4 r; r.x = axB; r.y = ayB; r.z = azB; r.w = awB;
        *(float4*)(out + ((size_t)rowB << 6) + col4) = r;
    }
}

extern "C" void kernel_launch(void* const* d_in, const int* in_sizes, int n_in,
                              void* d_out, int out_size, void* d_ws, size_t ws_size,
                              hipStream_t stream) {
    const float* x       = (const float*)d_in[0];
    const int*   indptr  = (const int*)  d_in[1];
    const int*   indices = (const int*)  d_in[2];
    const float* values  = (const float*)d_in[3];
    float*       out     = (float*)d_out;

    const int n_nodes = in_sizes[1] - 1;   // indptr has N+1 entries
    const int n_edges = in_sizes[2];

    const int threads = 256;               // 4 waves/block, 2 rows/wave -> 8 rows/block
    const int waves   = (n_nodes + 1) / 2;
    const int blocks  = (waves + 3) / 4;

    spmm_dualrow_kernel<<<blocks, threads, 0, stream>>>(
        x, indptr, indices, values, out, n_nodes, n_edges);
}

// Round 6
// 53.184 us; speedup vs baseline: 1.4242x; 1.4242x over previous
//
#include <hip/hip_runtime.h>
#include <hip/hip_fp16.h>

#define DIM 64

// ---------- pass 1: compress x (f32) -> xh (fp16) in workspace ----------
__global__ __launch_bounds__(256) void cvt_half_kernel(
    const float* __restrict__ x, __half* __restrict__ xh, int n4)
{
    int i = blockIdx.x * blockDim.x + threadIdx.x;
    const int stride = gridDim.x * blockDim.x;
    for (; i < n4; i += stride) {
        const float4 v = ((const float4*)x)[i];
        __half2 h0 = __floats2half2_rn(v.x, v.y);
        __half2 h1 = __floats2half2_rn(v.z, v.w);
        uint2 u;
        u.x = *(const unsigned int*)&h0;
        u.y = *(const unsigned int*)&h1;
        ((uint2*)xh)[i] = u;
    }
}

// ---------- pass 2: CSR SpMM over fp16 x ----------
// One wave per row. 8 groups x 8 lanes; group g owns edge k+g, lane reads
// 16B (8 halves) of that edge's x-row -> one dwordx4 instruction moves
// 8 edges' rows (1 KiB, 8 cache lines: 1 line per edge).
// f32 accumulate; 3-round shfl_xor (8,16,32) reduction; lanes 0-7 store.
__global__ __launch_bounds__(256) void spmm_half_kernel(
    const __half* __restrict__ xh,
    const int*   __restrict__ indptr,
    const int*   __restrict__ indices,
    const float* __restrict__ values,
    float*       __restrict__ out,
    int n_nodes)
{
    const int row  = (int)((blockIdx.x * blockDim.x + threadIdx.x) >> 6);
    const int lane = (int)(threadIdx.x & 63);
    if (row >= n_nodes) return;
    const int g = lane >> 3;        // edge slot 0..7
    const int t = lane & 7;         // column octet: cols [t*8, t*8+8)

    const int start = indptr[row];
    const int end   = indptr[row + 1];

    float a0=0.f,a1=0.f,a2=0.f,a3=0.f,a4=0.f,a5=0.f,a6=0.f,a7=0.f;

    if (start < end) {
        const int last = end - 1;
        for (int k = start; k < end; k += 16) {
            const int e0 = k + g;
            const int e1 = k + 8 + g;
            const int ce0 = (e0 <= last) ? e0 : last;   // clamp: dup gathers hit same line
            const int ce1 = (e1 <= last) ? e1 : last;
            const int c0 = indices[ce0];
            const int c1 = indices[ce1];
            const float w0 = (e0 <= last) ? values[ce0] : 0.0f;
            const float w1 = (e1 <= last) ? values[ce1] : 0.0f;

            const uint4 p0 = *(const uint4*)(xh + (((unsigned)c0) << 6) + (t << 3));
            const uint4 p1 = *(const uint4*)(xh + (((unsigned)c1) << 6) + (t << 3));

            float2 f;
            f = __half22float2(*(const __half2*)&p0.x); a0 += w0*f.x; a1 += w0*f.y;
            f = __half22float2(*(const __half2*)&p0.y); a2 += w0*f.x; a3 += w0*f.y;
            f = __half22float2(*(const __half2*)&p0.z); a4 += w0*f.x; a5 += w0*f.y;
            f = __half22float2(*(const __half2*)&p0.w); a6 += w0*f.x; a7 += w0*f.y;
            f = __half22float2(*(const __half2*)&p1.x); a0 += w1*f.x; a1 += w1*f.y;
            f = __half22float2(*(const __half2*)&p1.y); a2 += w1*f.x; a3 += w1*f.y;
            f = __half22float2(*(const __half2*)&p1.z); a4 += w1*f.x; a5 += w1*f.y;
            f = __half22float2(*(const __half2*)&p1.w); a6 += w1*f.x; a7 += w1*f.y;
        }
    }

    // Sum the 8 edge-groups: lanes {l^8, l^16, l^32} hold the same columns.
#define RED(m) a0+=__shfl_xor(a0,m); a1+=__shfl_xor(a1,m); a2+=__shfl_xor(a2,m); a3+=__shfl_xor(a3,m); \
               a4+=__shfl_xor(a4,m); a5+=__shfl_xor(a5,m); a6+=__shfl_xor(a6,m); a7+=__shfl_xor(a7,m);
    RED(8) RED(16) RED(32)
#undef RED

    if (lane < 8) {
        float4 r0; r0.x=a0; r0.y=a1; r0.z=a2; r0.w=a3;
        float4 r1; r1.x=a4; r1.y=a5; r1.z=a6; r1.w=a7;
        float* dst = out + (((size_t)row) << 6) + (t << 3);
        *(float4*)(dst)     = r0;
        *(float4*)(dst + 4) = r1;
    }
}

// ---------- fallback (ws too small): round-3 f32 quad kernel ----------
__global__ __launch_bounds__(256) void spmm_quad_kernel(
    const float* __restrict__ x,
    const int*   __restrict__ indptr,
    const int*   __restrict__ indices,
    const float* __restrict__ values,
    float*       __restrict__ out,
    int n_nodes)
{
    const int row  = (int)((blockIdx.x * blockDim.x + threadIdx.x) >> 6);
    const int lane = (int)(threadIdx.x & 63);
    if (row >= n_nodes) return;

    const int start = indptr[row];
    const int end   = indptr[row + 1];
    const int g     = lane >> 4;
    const unsigned col4 = (unsigned)(lane & 15) << 2;

    float ax = 0.f, ay = 0.f, az = 0.f, aw = 0.f;

    if (start < end) {
        const int last = end - 1;
        for (int k = start; k < end; k += 16) {
            const int e0 = k +  0 + g, e1 = k + 4 + g, e2 = k + 8 + g, e3 = k + 12 + g;
            const int ce0 = e0 <= last ? e0 : last;
            const int ce1 = e1 <= last ? e1 : last;
            const int ce2 = e2 <= last ? e2 : last;
            const int ce3 = e3 <= last ? e3 : last;
            const int c0 = indices[ce0], c1 = indices[ce1];
            const int c2 = indices[ce2], c3 = indices[ce3];
            const float w0 = (e0 <= last) ? values[ce0] : 0.0f;
            const float w1 = (e1 <= last) ? values[ce1] : 0.0f;
            const float w2 = (e2 <= last) ? values[ce2] : 0.0f;
            const float w3 = (e3 <= last) ? values[ce3] : 0.0f;
            const float4 a0 = *(const float4*)(x + (((unsigned)c0) << 6) + col4);
            const float4 a1 = *(const float4*)(x + (((unsigned)c1) << 6) + col4);
            const float4 a2 = *(const float4*)(x + (((unsigned)c2) << 6) + col4);
            const float4 a3 = *(const float4*)(x + (((unsigned)c3) << 6) + col4);
            ax += w0 * a0.x; ay += w0 * a0.y; az += w0 * a0.z; aw += w0 * a0.w;
            ax += w1 * a1.x; ay += w1 * a1.y; az += w1 * a1.z; aw += w1 * a1.w;
            ax += w2 * a2.x; ay += w2 * a2.y; az += w2 * a2.z; aw += w2 * a2.w;
            ax += w3 * a3.x; ay += w3 * a3.y; az += w3 * a3.z; aw += w3 * a3.w;
        }
    }

    ax += __shfl_xor(ax, 16); ay += __shfl_xor(ay, 16);
    az += __shfl_xor(az, 16); aw += __shfl_xor(aw, 16);
    ax += __shfl_xor(ax, 32); ay += __shfl_xor(ay, 32);
    az += __shfl_xor(az, 32); aw += __shfl_xor(aw, 32);

    if (lane < 16) {
        float4 r; r.x = ax; r.y = ay; r.z = az; r.w = aw;
        *(float4*)(out + ((size_t)row << 6) + col4) = r;
    }
}

extern "C" void kernel_launch(void* const* d_in, const int* in_sizes, int n_in,
                              void* d_out, int out_size, void* d_ws, size_t ws_size,
                              hipStream_t stream) {
    const float* x       = (const float*)d_in[0];
    const int*   indptr  = (const int*)  d_in[1];
    const int*   indices = (const int*)  d_in[2];
    const float* values  = (const float*)d_in[3];
    float*       out     = (float*)d_out;

    const int n_nodes = in_sizes[1] - 1;     // indptr has N+1 entries
    const int n_xelem = in_sizes[0];         // N * 64

    const int threads = 256;
    const int rows_per_block = threads / 64;
    const int blocks = (n_nodes + rows_per_block - 1) / rows_per_block;

    const size_t needed = (size_t)n_xelem * sizeof(__half);
    if (ws_size >= needed) {
        __half* xh = (__half*)d_ws;
        const int n4 = n_xelem / 4;
        cvt_half_kernel<<<2048, 256, 0, stream>>>(x, xh, n4);
        spmm_half_kernel<<<blocks, threads, 0, stream>>>(
            xh, indptr, indices, values, out, n_nodes);
    } else {
        spmm_quad_kernel<<<blocks, threads, 0, stream>>>(
            x, indptr, indices, values, out, n_nodes);
    }
}

// Round 7
// 52.449 us; speedup vs baseline: 1.4441x; 1.0140x over previous
//
#include <hip/hip_runtime.h>
#include <hip/hip_fp16.h>

#define DIM 64

// ---------- pass 1: compress x (f32) -> xh (fp16) in workspace ----------
__global__ __launch_bounds__(256) void cvt_half_kernel(
    const float* __restrict__ x, __half* __restrict__ xh, int n4)
{
    int i = blockIdx.x * blockDim.x + threadIdx.x;
    const int stride = gridDim.x * blockDim.x;
    for (; i < n4; i += stride) {
        const float4 v = ((const float4*)x)[i];
        __half2 h0 = __floats2half2_rn(v.x, v.y);
        __half2 h1 = __floats2half2_rn(v.z, v.w);
        uint2 u;
        u.x = *(const unsigned int*)&h0;
        u.y = *(const unsigned int*)&h1;
        ((uint2*)xh)[i] = u;
    }
}

// unpack 8 halves (uint4) and FMA into acc[8] with weight W
#define UNPACK_FMA(P, W, A)                                                    \
    { float2 f_;                                                               \
      f_ = __half22float2(*(const __half2*)&(P).x); (A)[0]+=(W)*f_.x; (A)[1]+=(W)*f_.y; \
      f_ = __half22float2(*(const __half2*)&(P).y); (A)[2]+=(W)*f_.x; (A)[3]+=(W)*f_.y; \
      f_ = __half22float2(*(const __half2*)&(P).z); (A)[4]+=(W)*f_.x; (A)[5]+=(W)*f_.y; \
      f_ = __half22float2(*(const __half2*)&(P).w); (A)[6]+=(W)*f_.x; (A)[7]+=(W)*f_.y; }

// one 16-edge clamped tile of one row
#define ROW_TILE(K, LAST, ACC)                                                 \
    { const int e0_ = (K) + g, e1_ = (K) + 8 + g;                              \
      const int i0_ = e0_ <= (LAST) ? e0_ : (LAST);                            \
      const int i1_ = e1_ <= (LAST) ? e1_ : (LAST);                            \
      const int c0_ = indices[i0_], c1_ = indices[i1_];                        \
      const float w0_ = (e0_ <= (LAST)) ? values[i0_] : 0.f;                   \
      const float w1_ = (e1_ <= (LAST)) ? values[i1_] : 0.f;                   \
      const uint4 p0_ = *(const uint4*)(xh + (((unsigned)c0_) << 6) + (t << 3)); \
      const uint4 p1_ = *(const uint4*)(xh + (((unsigned)c1_) << 6) + (t << 3)); \
      UNPACK_FMA(p0_, w0_, ACC) UNPACK_FMA(p1_, w1_, ACC) }

// ---------- pass 2: CSR SpMM over fp16 x, TWO rows per wave ----------
// 8 groups x 8 lanes; group g owns edge slots k+g and k+8+g; lane reads 16B
// (8 halves) of that edge's x-row. Both rows' tiles issued in one straight-line
// body -> 4 x 1KiB gathers (32 lines) in flight per wave. All indices clamped
// to the row's own last edge (no cross-row pollution).
__global__ __launch_bounds__(256) void spmm_half_dual_kernel(
    const __half* __restrict__ xh,
    const int*   __restrict__ indptr,
    const int*   __restrict__ indices,
    const float* __restrict__ values,
    float*       __restrict__ out,
    int n_nodes)
{
    const int wave = (int)((blockIdx.x * blockDim.x + threadIdx.x) >> 6);
    const int lane = (int)(threadIdx.x & 63);
    const int rowA = wave << 1;
    const int rowB = rowA + 1;
    if (rowA >= n_nodes) return;

    const int g = lane >> 3;        // edge slot within tile
    const int t = lane & 7;         // column octet: cols [t*8, t*8+8)

    const int sA = indptr[rowA];
    const int eA = indptr[rowA + 1];
    const int eB = (rowB < n_nodes) ? indptr[rowB + 1] : eA;

    int kA = sA, kB = eA;           // row B starts where row A ends (CSR)
    const int lastA = eA - 1;       // valid only when row non-empty (loop-guarded)
    const int lastB = eB - 1;

    float aA[8] = {0.f,0.f,0.f,0.f,0.f,0.f,0.f,0.f};
    float aB[8] = {0.f,0.f,0.f,0.f,0.f,0.f,0.f,0.f};

    // both-rows phase: two dependency chains + 32 lines in flight
    while (kA < eA && kB < eB) {
        ROW_TILE(kA, lastA, aA)
        ROW_TILE(kB, lastB, aB)
        kA += 16; kB += 16;
    }
    // remainder: whichever row still has edges
    while (kA < eA) { ROW_TILE(kA, lastA, aA) kA += 16; }
    while (kB < eB) { ROW_TILE(kB, lastB, aB) kB += 16; }

    // Sum the 8 edge-groups: lanes {l^8, l^16, l^32} hold the same columns.
#define RED(A, m) (A)[0]+=__shfl_xor((A)[0],m); (A)[1]+=__shfl_xor((A)[1],m); \
                  (A)[2]+=__shfl_xor((A)[2],m); (A)[3]+=__shfl_xor((A)[3],m); \
                  (A)[4]+=__shfl_xor((A)[4],m); (A)[5]+=__shfl_xor((A)[5],m); \
                  (A)[6]+=__shfl_xor((A)[6],m); (A)[7]+=__shfl_xor((A)[7],m);
    RED(aA, 8) RED(aA, 16) RED(aA, 32)
    RED(aB, 8) RED(aB, 16) RED(aB, 32)
#undef RED

    if (lane < 8) {
        float4 r0; r0.x=aA[0]; r0.y=aA[1]; r0.z=aA[2]; r0.w=aA[3];
        float4 r1; r1.x=aA[4]; r1.y=aA[5]; r1.z=aA[6]; r1.w=aA[7];
        float* dst = out + (((size_t)rowA) << 6) + (t << 3);
        *(float4*)(dst)     = r0;
        *(float4*)(dst + 4) = r1;
    } else if (lane < 16 && rowB < n_nodes) {
        float4 r0; r0.x=aB[0]; r0.y=aB[1]; r0.z=aB[2]; r0.w=aB[3];
        float4 r1; r1.x=aB[4]; r1.y=aB[5]; r1.z=aB[6]; r1.w=aB[7];
        float* dst = out + (((size_t)rowB) << 6) + (t << 3);
        *(float4*)(dst)     = r0;
        *(float4*)(dst + 4) = r1;
    }
}

// ---------- fallback (ws too small): f32 quad kernel (round 3) ----------
__global__ __launch_bounds__(256) void spmm_quad_kernel(
    const float* __restrict__ x,
    const int*   __restrict__ indptr,
    const int*   __restrict__ indices,
    const float* __restrict__ values,
    float*       __restrict__ out,
    int n_nodes)
{
    const int row  = (int)((blockIdx.x * blockDim.x + threadIdx.x) >> 6);
    const int lane = (int)(threadIdx.x & 63);
    if (row >= n_nodes) return;

    const int start = indptr[row];
    const int end   = indptr[row + 1];
    const int g     = lane >> 4;
    const unsigned col4 = (unsigned)(lane & 15) << 2;

    float ax = 0.f, ay = 0.f, az = 0.f, aw = 0.f;

    if (start < end) {
        const int last = end - 1;
        for (int k = start; k < end; k += 16) {
            const int e0 = k +  0 + g, e1 = k + 4 + g, e2 = k + 8 + g, e3 = k + 12 + g;
            const int ce0 = e0 <= last ? e0 : last;
            const int ce1 = e1 <= last ? e1 : last;
            const int ce2 = e2 <= last ? e2 : last;
            const int ce3 = e3 <= last ? e3 : last;
            const int c0 = indices[ce0], c1 = indices[ce1];
            const int c2 = indices[ce2], c3 = indices[ce3];
            const float w0 = (e0 <= last) ? values[ce0] : 0.0f;
            const float w1 = (e1 <= last) ? values[ce1] : 0.0f;
            const float w2 = (e2 <= last) ? values[ce2] : 0.0f;
            const float w3 = (e3 <= last) ? values[ce3] : 0.0f;
            const float4 a0 = *(const float4*)(x + (((unsigned)c0) << 6) + col4);
            const float4 a1 = *(const float4*)(x + (((unsigned)c1) << 6) + col4);
            const float4 a2 = *(const float4*)(x + (((unsigned)c2) << 6) + col4);
            const float4 a3 = *(const float4*)(x + (((unsigned)c3) << 6) + col4);
            ax += w0 * a0.x; ay += w0 * a0.y; az += w0 * a0.z; aw += w0 * a0.w;
            ax += w1 * a1.x; ay += w1 * a1.y; az += w1 * a1.z; aw += w1 * a1.w;
            ax += w2 * a2.x; ay += w2 * a2.y; az += w2 * a2.z; aw += w2 * a2.w;
            ax += w3 * a3.x; ay += w3 * a3.y; az += w3 * a3.z; aw += w3 * a3.w;
        }
    }

    ax += __shfl_xor(ax, 16); ay += __shfl_xor(ay, 16);
    az += __shfl_xor(az, 16); aw += __shfl_xor(aw, 16);
    ax += __shfl_xor(ax, 32); ay += __shfl_xor(ay, 32);
    az += __shfl_xor(az, 32); aw += __shfl_xor(aw, 32);

    if (lane < 16) {
        float4 r; r.x = ax; r.y = ay; r.z = az; r.w = aw;
        *(float4*)(out + ((size_t)row << 6) + col4) = r;
    }
}

extern "C" void kernel_launch(void* const* d_in, const int* in_sizes, int n_in,
                              void* d_out, int out_size, void* d_ws, size_t ws_size,
                              hipStream_t stream) {
    const float* x       = (const float*)d_in[0];
    const int*   indptr  = (const int*)  d_in[1];
    const int*   indices = (const int*)  d_in[2];
    const float* values  = (const float*)d_in[3];
    float*       out     = (float*)d_out;

    const int n_nodes = in_sizes[1] - 1;     // indptr has N+1 entries
    const int n_xelem = in_sizes[0];         // N * 64

    const size_t needed = (size_t)n_xelem * sizeof(__half);
    if (ws_size >= needed) {
        __half* xh = (__half*)d_ws;
        const int n4 = n_xelem / 4;
        cvt_half_kernel<<<2048, 256, 0, stream>>>(x, xh, n4);

        const int threads = 256;                 // 4 waves/block, 2 rows/wave
        const int waves   = (n_nodes + 1) / 2;
        const int blocks  = (waves + 3) / 4;
        spmm_half_dual_kernel<<<blocks, threads, 0, stream>>>(
            xh, indptr, indices, values, out, n_nodes);
    } else {
        const int threads = 256;
        const int blocks = (n_nodes + 3) / 4;
        spmm_quad_kernel<<<blocks, threads, 0, stream>>>(
            x, indptr, indices, values, out, n_nodes);
    }
}